// Round 1
// baseline (2743.492 us; speedup 1.0000x reference)
//
#include <hip/hip_runtime.h>
#include <math.h>
#include <stdint.h>

#define B_Q    512
#define N_BANK 100000
#define D_DIM  256
#define K16    16
#define BT     64          // queries per block tile
#define JT     64          // bank rows per chunk
#define KC     64          // K chunk
#define NSLICE 128
#define NCHUNK ((N_BANK + JT - 1) / JT)   // 1563

// workspace layout (bytes)
#define OFF_QN    0
#define OFF_INORM (B_Q * D_DIM * 4)                 // 524288
#define OFF_PSC   (1024 * 1024)                     // 1 MB
#define OFF_PID   (OFF_PSC + B_Q * NSLICE * K16 * 4) // 5 MB; end ~9 MB

// ---------------- kernel 1: qn = normalize(z_ego @ W^T) ----------------
__global__ void qn_kernel(const float* __restrict__ z_ego,
                          const float* __restrict__ W,
                          float* __restrict__ qn) {
    __shared__ float zs[D_DIM];
    __shared__ float red[4];
    int b = blockIdx.x;
    int t = threadIdx.x;
    zs[t] = z_ego[b * D_DIM + t];
    __syncthreads();
    const float4* W4 = reinterpret_cast<const float4*>(W + (size_t)t * D_DIM);
    float acc = 0.f;
#pragma unroll 8
    for (int u = 0; u < 64; ++u) {
        float4 w = W4[u];
        acc += w.x * zs[u * 4 + 0];
        acc += w.y * zs[u * 4 + 1];
        acc += w.z * zs[u * 4 + 2];
        acc += w.w * zs[u * 4 + 3];
    }
    float ss = acc * acc;
#pragma unroll
    for (int off = 32; off > 0; off >>= 1) ss += __shfl_down(ss, off, 64);
    if ((t & 63) == 0) red[t >> 6] = ss;
    __syncthreads();
    float tot = red[0] + red[1] + red[2] + red[3];
    float n = fmaxf(sqrtf(tot), 1e-12f);
    qn[b * D_DIM + t] = acc / n;
}

// ---------------- kernel 2: inorm[j] = 1/max(||bank_j||, eps) ----------------
__global__ void inorm_kernel(const float* __restrict__ bank,
                             float* __restrict__ inorm) {
    int w = threadIdx.x >> 6;
    int lane = threadIdx.x & 63;
    int j = blockIdx.x * 4 + w;
    if (j >= N_BANK) return;
    const float4* r4 = reinterpret_cast<const float4*>(bank + (size_t)j * D_DIM);
    float4 v = r4[lane];
    float ss = v.x * v.x + v.y * v.y + v.z * v.z + v.w * v.w;
#pragma unroll
    for (int off = 32; off > 0; off >>= 1) ss += __shfl_down(ss, off, 64);
    if (lane == 0) inorm[j] = 1.0f / fmaxf(sqrtf(ss), 1e-12f);
}

// ---------------- kernel 3: fused score GEMM + per-slice top-16 ----------------
__global__ __launch_bounds__(256)
void score_topk_kernel(const float* __restrict__ qn,
                       const float* __restrict__ bank,
                       const float* __restrict__ svt,
                       const float* __restrict__ inorm,
                       float* __restrict__ psc,
                       int* __restrict__ pid) {
    __shared__ float As[KC][BT];       // [k][q]
    __shared__ float Bs[KC][JT];       // [k][j]
    __shared__ float Ss[BT][JT + 1];   // score tile, padded

    int slice = blockIdx.x;
    int qbase = blockIdx.y * BT;
    int t  = threadIdx.x;
    int tq = t >> 4;          // 0..15
    int tj = t & 15;          // 0..15
    int q0 = tq * 4;
    int j0l = tj * 4;

    // per-owner running top-16 (only meaningful for t < 64)
    float sc[K16];
    int   id[K16];
#pragma unroll
    for (int i = 0; i < K16; ++i) { sc[i] = -INFINITY; id[i] = 0x7fffffff; }

    for (int c = slice; c < NCHUNK; c += NSLICE) {
        int j0 = c * JT;
        float acc[4][4];
#pragma unroll
        for (int a = 0; a < 4; ++a)
#pragma unroll
            for (int b2 = 0; b2 < 4; ++b2) acc[a][b2] = 0.f;

        for (int kc = 0; kc < D_DIM; kc += KC) {
            __syncthreads();   // protect LDS from previous iteration's readers
            // stage A: As[k][q] = qn[qbase+q][kc+k]
#pragma unroll
            for (int r = 0; r < 4; ++r) {
                int idx = t + 256 * r;
                int q  = idx & 63;
                int kv = idx >> 6;    // 0..15
                float4 v = *reinterpret_cast<const float4*>(
                    &qn[(size_t)(qbase + q) * D_DIM + kc + kv * 4]);
                As[kv * 4 + 0][q] = v.x;
                As[kv * 4 + 1][q] = v.y;
                As[kv * 4 + 2][q] = v.z;
                As[kv * 4 + 3][q] = v.w;
            }
            // stage B: Bs[k][j] = bank[j0+j][kc+k] (raw; inorm applied later)
#pragma unroll
            for (int r = 0; r < 4; ++r) {
                int idx = t + 256 * r;
                int j  = idx & 63;
                int kv = idx >> 6;
                int jg = j0 + j;
                float4 v = make_float4(0.f, 0.f, 0.f, 0.f);
                if (jg < N_BANK)
                    v = *reinterpret_cast<const float4*>(
                        &bank[(size_t)jg * D_DIM + kc + kv * 4]);
                Bs[kv * 4 + 0][j] = v.x;
                Bs[kv * 4 + 1][j] = v.y;
                Bs[kv * 4 + 2][j] = v.z;
                Bs[kv * 4 + 3][j] = v.w;
            }
            __syncthreads();
#pragma unroll
            for (int k = 0; k < KC; ++k) {
                float4 av = *reinterpret_cast<const float4*>(&As[k][q0]);
                float4 bv = *reinterpret_cast<const float4*>(&Bs[k][j0l]);
                float a[4] = {av.x, av.y, av.z, av.w};
                float b[4] = {bv.x, bv.y, bv.z, bv.w};
#pragma unroll
                for (int qi = 0; qi < 4; ++qi)
#pragma unroll
                    for (int ji = 0; ji < 4; ++ji)
                        acc[qi][ji] += a[qi] * b[ji];
            }
        }

        // epilogue: score = 0.5*sim_vv + 0.5*sim_vt into Ss
        bool full = (j0 + JT <= N_BANK);
        if (full) {
            float4 inv = *reinterpret_cast<const float4*>(&inorm[j0 + j0l]);
            float iv[4] = {inv.x, inv.y, inv.z, inv.w};
#pragma unroll
            for (int qi = 0; qi < 4; ++qi) {
                int q = qbase + q0 + qi;
                float4 sv = *reinterpret_cast<const float4*>(
                    &svt[(size_t)q * N_BANK + j0 + j0l]);
                float s[4] = {sv.x, sv.y, sv.z, sv.w};
#pragma unroll
                for (int ji = 0; ji < 4; ++ji)
                    Ss[q0 + qi][j0l + ji] = 0.5f * (acc[qi][ji] * iv[ji]) + 0.5f * s[ji];
            }
        } else {
#pragma unroll
            for (int qi = 0; qi < 4; ++qi) {
                int q = qbase + q0 + qi;
#pragma unroll
                for (int ji = 0; ji < 4; ++ji) {
                    int jg = j0 + j0l + ji;
                    float s = -INFINITY;
                    if (jg < N_BANK)
                        s = 0.5f * (acc[qi][ji] * inorm[jg]) +
                            0.5f * svt[(size_t)q * N_BANK + jg];
                    Ss[q0 + qi][j0l + ji] = s;
                }
            }
        }
        __syncthreads();

        // owner scan: thread t (<64) owns query qbase+t
        if (t < BT) {
#pragma unroll 1
            for (int jj = 0; jj < JT; ++jj) {
                int jg = j0 + jj;
                if (jg >= N_BANK) break;
                float s = Ss[t][jj];
                if (s > sc[K16 - 1] || (s == sc[K16 - 1] && jg < id[K16 - 1])) {
                    float cs = s; int ci = jg;
#pragma unroll
                    for (int i = 0; i < K16; ++i) {
                        bool bt2 = (cs > sc[i]) || (cs == sc[i] && ci < id[i]);
                        float ts = sc[i]; int ti = id[i];
                        if (bt2) { sc[i] = cs; id[i] = ci; cs = ts; ci = ti; }
                    }
                }
            }
        }
        // next chunk's first __syncthreads() protects Ss/As/Bs
    }

    if (t < BT) {
        int q = qbase + t;
        size_t base = ((size_t)q * NSLICE + slice) * K16;
#pragma unroll
        for (int i = 0; i < K16; ++i) {
            psc[base + i] = sc[i];
            pid[base + i] = id[i];
        }
    }
}

// ---------------- kernel 4: merge partials, gather, write outputs ----------------
__device__ inline unsigned long long shfl_down_u64(unsigned long long x, int off) {
    unsigned int lo = (unsigned int)x;
    unsigned int hi = (unsigned int)(x >> 32);
    lo = __shfl_down(lo, off, 64);
    hi = __shfl_down(hi, off, 64);
    return ((unsigned long long)hi << 32) | lo;
}

__global__ __launch_bounds__(256)
void merge_kernel(const float* __restrict__ psc,
                  const int* __restrict__ pid,
                  const float* __restrict__ bank,
                  float* __restrict__ out) {
    __shared__ unsigned long long keys[NSLICE * K16];   // 2048 -> 16KB
    __shared__ unsigned long long wred[4];
    __shared__ int win[K16];
    int b = blockIdx.x;
    int t = threadIdx.x;

    for (int i = t; i < NSLICE * K16; i += 256) {
        float s = psc[(size_t)b * NSLICE * K16 + i];
        unsigned int u = __float_as_uint(s);
        u ^= (u & 0x80000000u) ? 0xFFFFFFFFu : 0x80000000u;  // order-preserving map
        unsigned int iv = ~(unsigned int)pid[(size_t)b * NSLICE * K16 + i];
        keys[i] = ((unsigned long long)u << 32) | iv;        // (score desc, idx asc)
    }
    __syncthreads();

    for (int r = 0; r < K16; ++r) {
        unsigned long long best = 0ull;
        for (int i = t; i < NSLICE * K16; i += 256) {
            unsigned long long k = keys[i];
            if (k > best) best = k;
        }
#pragma unroll
        for (int off = 32; off > 0; off >>= 1) {
            unsigned long long o = shfl_down_u64(best, off);
            if (o > best) best = o;
        }
        if ((t & 63) == 0) wred[t >> 6] = best;
        __syncthreads();
        unsigned long long w0 = wred[0] > wred[1] ? wred[0] : wred[1];
        unsigned long long w1 = wred[2] > wred[3] ? wred[2] : wred[3];
        unsigned long long w = w0 > w1 ? w0 : w1;
        if (t == 0) win[r] = (int)(~(unsigned int)w);
        for (int i = t; i < NSLICE * K16; i += 256)
            if (keys[i] == w) keys[i] = 0ull;
        __syncthreads();
    }

    // indices (as float) after the gathered block
    if (t < K16)
        out[(size_t)B_Q * K16 * D_DIM + (size_t)b * K16 + t] = (float)win[t];

    // gather rows: 16 rows x 64 float4
    const float4* bank4 = reinterpret_cast<const float4*>(bank);
    float4* out4 = reinterpret_cast<float4*>(out);
    for (int u = t; u < K16 * 64; u += 256) {
        int r = u >> 6;
        int c = u & 63;
        float4 v = bank4[(size_t)win[r] * 64 + c];
        out4[((size_t)b * K16 + r) * 64 + c] = v;
    }
}

// ---------------- launcher ----------------
extern "C" void kernel_launch(void* const* d_in, const int* in_sizes, int n_in,
                              void* d_out, int out_size, void* d_ws, size_t ws_size,
                              hipStream_t stream) {
    const float* z_ego = (const float*)d_in[0];
    const float* bank  = (const float*)d_in[1];
    const float* svt   = (const float*)d_in[2];
    const float* W     = (const float*)d_in[3];
    float* out = (float*)d_out;

    char* ws = (char*)d_ws;
    float* qn    = (float*)(ws + OFF_QN);
    float* inorm = (float*)(ws + OFF_INORM);
    float* psc   = (float*)(ws + OFF_PSC);
    int*   pid   = (int*)(ws + OFF_PID);

    qn_kernel<<<B_Q, 256, 0, stream>>>(z_ego, W, qn);
    inorm_kernel<<<(N_BANK + 3) / 4, 256, 0, stream>>>(bank, inorm);
    dim3 grid(NSLICE, B_Q / BT);
    score_topk_kernel<<<grid, 256, 0, stream>>>(qn, bank, svt, inorm, psc, pid);
    merge_kernel<<<B_Q, 256, 0, stream>>>(psc, pid, bank, out);
}

// Round 2
// 1204.993 us; speedup vs baseline: 2.2768x; 2.2768x over previous
//
#include <hip/hip_runtime.h>
#include <math.h>
#include <stdint.h>

#define B_Q    512
#define N_BANK 100000
#define D_DIM  256
#define K16    16

// ---------------- new (MFMA) path constants ----------------
#define NSLICE 64
#define NW     4
#define POOL   (NSLICE * NW * K16)          // 4096 candidates/query
#define NCHUNK 1563                          // ceil(100000/64)
#define TROW   264                           // bf16 elems per padded row (256 + 8 pad)
#define CHUNK_USHORT (64 * TROW)             // 16896
#define CHUNK_BYTES  (CHUNK_USHORT * 2)      // 33792
#define MARGIN 1.2e-3f
#define CAP    512

// new-path ws layout (bytes)
#define OFF_QN     0                 // fp32 qn: 512*256*4 = 524288
#define OFF_QNT    0x80000           // bf16 tiled qn: 8*33792 = 270336
#define OFF_INORM  0x100000          // fp32 inorm: 400000
#define OFF_PSC    0x180000          // fp32 partial scores: 512*4096*4 = 8 MB
#define OFF_PID    0xB80000          // int partial ids: 8 MB
#define OFF_BANKN  0x1400000         // bf16 tiled bank: 1563*33792 = 52816896
#define WS_NEED    ((size_t)OFF_BANKN + (size_t)NCHUNK * CHUNK_BYTES)

// old (fallback) path ws layout
#define FB_OFF_INORM (B_Q * D_DIM * 4)
#define FB_OFF_PSC   (1024 * 1024)
#define FB_OFF_PID   (FB_OFF_PSC + B_Q * 128 * K16 * 4)

typedef __attribute__((ext_vector_type(8))) short short8;
typedef __attribute__((ext_vector_type(4))) float floatx4;

// ---------------- helpers ----------------
__device__ inline unsigned short f2bf(float x) {   // RNE fp32 -> bf16
    unsigned int u = __float_as_uint(x);
    unsigned int r = (u + 0x7FFFu + ((u >> 16) & 1u)) >> 16;
    return (unsigned short)r;
}
__device__ inline unsigned long long pack_key(float s, int idx) {
    unsigned int u = __float_as_uint(s);
    u ^= (u & 0x80000000u) ? 0xFFFFFFFFu : 0x80000000u;  // order-preserving
    return ((unsigned long long)u << 32) | (unsigned int)(~(unsigned int)idx);
}
__device__ inline float unflip(unsigned int u) {
    u ^= (u & 0x80000000u) ? 0x80000000u : 0xFFFFFFFFu;
    return __uint_as_float(u);
}
__device__ inline int key_idx(unsigned long long k) {
    return (int)(~(unsigned int)(k & 0xFFFFFFFFull));
}
__device__ inline unsigned long long shfl_down_u64(unsigned long long x, int off) {
    unsigned int lo = (unsigned int)x;
    unsigned int hi = (unsigned int)(x >> 32);
    lo = __shfl_down(lo, off, 64);
    hi = __shfl_down(hi, off, 64);
    return ((unsigned long long)hi << 32) | lo;
}
__device__ inline unsigned long long umax64(unsigned long long a, unsigned long long b) {
    return a > b ? a : b;
}

// ================= NEW PATH =================

// qn = normalize(z_ego @ W^T) fp32, plus bf16 padded-tiled copy
__global__ void qn_prep_kernel(const float* __restrict__ z_ego,
                               const float* __restrict__ W,
                               float* __restrict__ qn,
                               unsigned short* __restrict__ qnt) {
    __shared__ float zs[D_DIM];
    __shared__ float red[4];
    int b = blockIdx.x;
    int t = threadIdx.x;
    zs[t] = z_ego[b * D_DIM + t];
    __syncthreads();
    const float4* W4 = reinterpret_cast<const float4*>(W + (size_t)t * D_DIM);
    float acc = 0.f;
#pragma unroll 8
    for (int u = 0; u < 64; ++u) {
        float4 w = W4[u];
        acc += w.x * zs[u * 4 + 0];
        acc += w.y * zs[u * 4 + 1];
        acc += w.z * zs[u * 4 + 2];
        acc += w.w * zs[u * 4 + 3];
    }
    float ss = acc * acc;
#pragma unroll
    for (int off = 32; off > 0; off >>= 1) ss += __shfl_down(ss, off, 64);
    if ((t & 63) == 0) red[t >> 6] = ss;
    __syncthreads();
    float tot = red[0] + red[1] + red[2] + red[3];
    float n = fmaxf(sqrtf(tot), 1e-12f);
    float v = acc / n;
    qn[b * D_DIM + t] = v;
    qnt[(size_t)(b >> 6) * CHUNK_USHORT + (size_t)(b & 63) * TROW + t] = f2bf(v);
}

__global__ void inorm_kernel(const float* __restrict__ bank,
                             float* __restrict__ inorm) {
    int w = threadIdx.x >> 6;
    int lane = threadIdx.x & 63;
    int j = blockIdx.x * 4 + w;
    if (j >= N_BANK) return;
    const float4* r4 = reinterpret_cast<const float4*>(bank + (size_t)j * D_DIM);
    float4 v = r4[lane];
    float ss = v.x * v.x + v.y * v.y + v.z * v.z + v.w * v.w;
#pragma unroll
    for (int off = 32; off > 0; off >>= 1) ss += __shfl_down(ss, off, 64);
    if (lane == 0) inorm[j] = 1.0f / fmaxf(sqrtf(ss), 1e-12f);
}

// bankn_tiled[c][64][264] bf16 = normalize(bank) rows, padded stride
__global__ void convert_kernel(const float* __restrict__ bank,
                               const float* __restrict__ inorm,
                               unsigned short* __restrict__ bankt) {
    int c = blockIdx.x;
    int t = threadIdx.x;
    int j0 = c * 64;
    unsigned short* dst = bankt + (size_t)c * CHUNK_USHORT;
#pragma unroll
    for (int i = 0; i < 16; ++i) {
        int f = t + 256 * i;          // float4 index within 64x256 tile
        int r = f >> 6;
        int k4 = f & 63;
        int jg = j0 + r;
        ushort4 o;
        if (jg < N_BANK) {
            float inv = inorm[jg];
            float4 v = *reinterpret_cast<const float4*>(bank + (size_t)jg * D_DIM + k4 * 4);
            o.x = f2bf(v.x * inv); o.y = f2bf(v.y * inv);
            o.z = f2bf(v.z * inv); o.w = f2bf(v.w * inv);
        } else {
            o.x = o.y = o.z = o.w = 0;
        }
        *reinterpret_cast<ushort4*>(dst + (size_t)r * TROW + k4 * 4) = o;
    }
}

// MFMA screening + fused per-(slice,wave) top-16
__global__ __launch_bounds__(256, 2)
void score_mfma_kernel(const unsigned short* __restrict__ qnt,
                       const unsigned short* __restrict__ bankt,
                       const float* __restrict__ svt,
                       float* __restrict__ psc,
                       int* __restrict__ pid) {
    __shared__ __align__(16) unsigned short Bs[CHUNK_USHORT];  // 33792 B
    __shared__ float Sw[NW][64][17];                           // 17408 B

    int t = threadIdx.x;
    int w = t >> 6, l = t & 63;
    int lane16 = l & 15, quad = l >> 4;
    int qt = blockIdx.x & 7;
    int slice = blockIdx.x >> 3;
    int qbase = qt * 64;

    // A fragments resident in registers: 4 q-subtiles x 8 k-steps
    short8 afrag[4][8];
    {
        const unsigned short* base = qnt + (size_t)qt * CHUNK_USHORT;
#pragma unroll
        for (int s = 0; s < 4; ++s)
#pragma unroll
            for (int k = 0; k < 8; ++k)
                afrag[s][k] = *reinterpret_cast<const short8*>(
                    base + (size_t)(16 * s + lane16) * TROW + k * 32 + quad * 8);
    }

    float sc[K16];
    int   id[K16];
#pragma unroll
    for (int i = 0; i < K16; ++i) { sc[i] = -INFINITY; id[i] = 0x7fffffff; }

    for (int c = slice; c < NCHUNK; c += NSLICE) {
        __syncthreads();  // previous chunk's readers done
        // stage B chunk (33792 B) with b128 copies
        {
            const char* src = reinterpret_cast<const char*>(bankt) + (size_t)c * CHUNK_BYTES;
            char* dstc = reinterpret_cast<char*>(Bs);
#pragma unroll
            for (int i = 0; i < 9; ++i) {
                int off = t * 16 + i * 4096;
                if (off < CHUNK_BYTES)
                    *reinterpret_cast<uint4*>(dstc + off) =
                        *reinterpret_cast<const uint4*>(src + off);
            }
        }
        int j0 = c * 64;
        int jglob = j0 + 16 * w + lane16;
        // prefetch svt values for this chunk
        float sv[4][4];
#pragma unroll
        for (int s = 0; s < 4; ++s)
#pragma unroll
            for (int r = 0; r < 4; ++r) {
                int q = qbase + 16 * s + 4 * quad + r;
                sv[s][r] = (jglob < N_BANK) ? svt[(size_t)q * N_BANK + jglob] : 0.f;
            }
        __syncthreads();  // Bs ready

        floatx4 acc[4];
#pragma unroll
        for (int s = 0; s < 4; ++s) acc[s] = (floatx4){0.f, 0.f, 0.f, 0.f};

#pragma unroll
        for (int k = 0; k < 8; ++k) {
            short8 bfrag = *reinterpret_cast<const short8*>(
                Bs + (size_t)(16 * w + lane16) * TROW + k * 32 + quad * 8);
#pragma unroll
            for (int s = 0; s < 4; ++s)
                acc[s] = __builtin_amdgcn_mfma_f32_16x16x32_bf16(afrag[s][k], bfrag, acc[s], 0, 0, 0);
        }

        // epilogue: screened score -> per-wave LDS region
#pragma unroll
        for (int s = 0; s < 4; ++s)
#pragma unroll
            for (int r = 0; r < 4; ++r) {
                float score = (jglob < N_BANK) ? (0.5f * acc[s][r] + 0.5f * sv[s][r]) : -INFINITY;
                Sw[w][16 * s + 4 * quad + r][lane16] = score;
            }
        __syncthreads();

        // owner scan: thread (w,l) owns query qbase+l, cols of wave w
#pragma unroll 1
        for (int jj = 0; jj < 16; ++jj) {
            float s = Sw[w][l][jj];
            int jg = j0 + 16 * w + jj;
            if (s > sc[K16 - 1] || (s == sc[K16 - 1] && jg < id[K16 - 1])) {
                float cs = s; int ci = jg;
#pragma unroll
                for (int i = 0; i < K16; ++i) {
                    bool bt2 = (cs > sc[i]) || (cs == sc[i] && ci < id[i]);
                    float ts = sc[i]; int ti = id[i];
                    if (bt2) { sc[i] = cs; id[i] = ci; cs = ts; ci = ti; }
                }
            }
        }
    }

    // write partials: layout q-major -> [q][slice][w][16]
    size_t base = (((size_t)(qbase + l) * NSLICE + slice) * NW + w) * K16;
#pragma unroll
    for (int i = 0; i < K16; ++i) {
        psc[base + i] = sc[i];
        pid[base + i] = id[i];
    }
}

// per-query: screened top-16 -> threshold -> collect -> exact fp32 rescore -> top-16 -> gather
__global__ __launch_bounds__(256)
void select_rescore_kernel(const float* __restrict__ psc,
                           const int* __restrict__ pid,
                           const float* __restrict__ qn,
                           const float* __restrict__ inorm,
                           const float* __restrict__ bank,
                           const float* __restrict__ svt,
                           float* __restrict__ out) {
    __shared__ unsigned long long keys[POOL];     // 32 KB
    __shared__ float qns[D_DIM];                  // 1 KB
    __shared__ unsigned long long win64[K16];
    __shared__ unsigned long long wred[4];
    __shared__ int cand[CAP];
    __shared__ unsigned long long keys2[CAP];
    __shared__ int cntS;
    __shared__ int winI[K16];

    int b = blockIdx.x, t = threadIdx.x;
    int w = t >> 6, l = t & 63;

    qns[t] = qn[(size_t)b * D_DIM + t];
    for (int i = t; i < POOL; i += 256)
        keys[i] = pack_key(psc[(size_t)b * POOL + i], pid[(size_t)b * POOL + i]);
    if (t == 0) cntS = K16;
    __syncthreads();

    // 16 rounds of argmax over screened pool
    for (int r = 0; r < K16; ++r) {
        unsigned long long best = 0ull;
        for (int i = t; i < POOL; i += 256) best = umax64(best, keys[i]);
#pragma unroll
        for (int off = 32; off > 0; off >>= 1) best = umax64(best, shfl_down_u64(best, off));
        if (l == 0) wred[w] = best;
        __syncthreads();
        unsigned long long W = umax64(umax64(wred[0], wred[1]), umax64(wred[2], wred[3]));
        if (t == 0) win64[r] = W;
        for (int i = t; i < POOL; i += 256)
            if (keys[i] == W) keys[i] = 0ull;
        __syncthreads();
    }

    // threshold = screened s16 - margin
    float s16 = unflip((unsigned int)(win64[K16 - 1] >> 32));
    float th = s16 - MARGIN;
    unsigned int thf = __float_as_uint(th);
    thf ^= (thf & 0x80000000u) ? 0xFFFFFFFFu : 0x80000000u;
    unsigned long long thkey = ((unsigned long long)thf) << 32;

    if (t < K16) cand[t] = key_idx(win64[t]);
    __syncthreads();
    for (int i = t; i < POOL; i += 256) {
        unsigned long long k = keys[i];          // winners already zeroed -> no dupes
        if (k >= thkey) {
            int p = atomicAdd(&cntS, 1);
            if (p < CAP) cand[p] = key_idx(k);
        }
    }
    __syncthreads();
    int cnt = cntS < CAP ? cntS : CAP;

    // exact fp32 rescore of survivors
    const float4* bank4 = reinterpret_cast<const float4*>(bank);
    const float4* q4 = reinterpret_cast<const float4*>(qns);
    float4 qv = q4[l];
    for (int c = w; c < cnt; c += NW) {
        int j = cand[c];
        float4 bv = bank4[(size_t)j * 64 + l];
        float d = qv.x * bv.x + qv.y * bv.y + qv.z * bv.z + qv.w * bv.w;
#pragma unroll
        for (int off = 32; off > 0; off >>= 1) d += __shfl_down(d, off, 64);
        if (l == 0) {
            float score = 0.5f * (d * inorm[j]) + 0.5f * svt[(size_t)b * N_BANK + j];
            keys2[c] = pack_key(score, j);
        }
    }
    __syncthreads();

    // exact top-16
    for (int r = 0; r < K16; ++r) {
        unsigned long long best = 0ull;
        for (int i = t; i < cnt; i += 256) best = umax64(best, keys2[i]);
#pragma unroll
        for (int off = 32; off > 0; off >>= 1) best = umax64(best, shfl_down_u64(best, off));
        if (l == 0) wred[w] = best;
        __syncthreads();
        unsigned long long W = umax64(umax64(wred[0], wred[1]), umax64(wred[2], wred[3]));
        if (t == 0) winI[r] = key_idx(W);
        for (int i = t; i < cnt; i += 256)
            if (keys2[i] == W) keys2[i] = 0ull;
        __syncthreads();
    }

    if (t < K16)
        out[(size_t)B_Q * K16 * D_DIM + (size_t)b * K16 + t] = (float)winI[t];
    float4* out4 = reinterpret_cast<float4*>(out);
    for (int u = t; u < K16 * 64; u += 256) {
        int r = u >> 6, cc = u & 63;
        out4[((size_t)b * K16 + r) * 64 + cc] = bank4[(size_t)winI[r] * 64 + cc];
    }
}

// ================= FALLBACK (verified round-1) PATH =================
#define FBT 64
#define FJT 64
#define FKC 64
#define FNS 128
#define FNC ((N_BANK + FJT - 1) / FJT)

__global__ void fb_qn_kernel(const float* __restrict__ z_ego,
                             const float* __restrict__ W,
                             float* __restrict__ qn) {
    __shared__ float zs[D_DIM];
    __shared__ float red[4];
    int b = blockIdx.x;
    int t = threadIdx.x;
    zs[t] = z_ego[b * D_DIM + t];
    __syncthreads();
    const float4* W4 = reinterpret_cast<const float4*>(W + (size_t)t * D_DIM);
    float acc = 0.f;
#pragma unroll 8
    for (int u = 0; u < 64; ++u) {
        float4 w = W4[u];
        acc += w.x * zs[u * 4 + 0]; acc += w.y * zs[u * 4 + 1];
        acc += w.z * zs[u * 4 + 2]; acc += w.w * zs[u * 4 + 3];
    }
    float ss = acc * acc;
#pragma unroll
    for (int off = 32; off > 0; off >>= 1) ss += __shfl_down(ss, off, 64);
    if ((t & 63) == 0) red[t >> 6] = ss;
    __syncthreads();
    float tot = red[0] + red[1] + red[2] + red[3];
    qn[b * D_DIM + t] = acc / fmaxf(sqrtf(tot), 1e-12f);
}

__global__ __launch_bounds__(256)
void fb_score_topk_kernel(const float* __restrict__ qn,
                          const float* __restrict__ bank,
                          const float* __restrict__ svt,
                          const float* __restrict__ inorm,
                          float* __restrict__ psc,
                          int* __restrict__ pid) {
    __shared__ float As[FKC][FBT];
    __shared__ float Bsh[FKC][FJT];
    __shared__ float Ss[FBT][FJT + 1];
    int slice = blockIdx.x;
    int qbase = blockIdx.y * FBT;
    int t = threadIdx.x;
    int tq = t >> 4, tj = t & 15;
    int q0 = tq * 4, j0l = tj * 4;
    float sc[K16]; int id[K16];
#pragma unroll
    for (int i = 0; i < K16; ++i) { sc[i] = -INFINITY; id[i] = 0x7fffffff; }
    for (int c = slice; c < FNC; c += FNS) {
        int j0 = c * FJT;
        float acc[4][4];
#pragma unroll
        for (int a = 0; a < 4; ++a)
#pragma unroll
            for (int b2 = 0; b2 < 4; ++b2) acc[a][b2] = 0.f;
        for (int kc = 0; kc < D_DIM; kc += FKC) {
            __syncthreads();
#pragma unroll
            for (int r = 0; r < 4; ++r) {
                int idx = t + 256 * r;
                int q = idx & 63, kv = idx >> 6;
                float4 v = *reinterpret_cast<const float4*>(
                    &qn[(size_t)(qbase + q) * D_DIM + kc + kv * 4]);
                As[kv * 4 + 0][q] = v.x; As[kv * 4 + 1][q] = v.y;
                As[kv * 4 + 2][q] = v.z; As[kv * 4 + 3][q] = v.w;
            }
#pragma unroll
            for (int r = 0; r < 4; ++r) {
                int idx = t + 256 * r;
                int j = idx & 63, kv = idx >> 6;
                int jg = j0 + j;
                float4 v = make_float4(0.f, 0.f, 0.f, 0.f);
                if (jg < N_BANK)
                    v = *reinterpret_cast<const float4*>(
                        &bank[(size_t)jg * D_DIM + kc + kv * 4]);
                Bsh[kv * 4 + 0][j] = v.x; Bsh[kv * 4 + 1][j] = v.y;
                Bsh[kv * 4 + 2][j] = v.z; Bsh[kv * 4 + 3][j] = v.w;
            }
            __syncthreads();
#pragma unroll
            for (int k = 0; k < FKC; ++k) {
                float4 av = *reinterpret_cast<const float4*>(&As[k][q0]);
                float4 bv = *reinterpret_cast<const float4*>(&Bsh[k][j0l]);
                float a[4] = {av.x, av.y, av.z, av.w};
                float bb[4] = {bv.x, bv.y, bv.z, bv.w};
#pragma unroll
                for (int qi = 0; qi < 4; ++qi)
#pragma unroll
                    for (int ji = 0; ji < 4; ++ji) acc[qi][ji] += a[qi] * bb[ji];
            }
        }
        bool full = (j0 + FJT <= N_BANK);
        if (full) {
            float4 inv = *reinterpret_cast<const float4*>(&inorm[j0 + j0l]);
            float iv[4] = {inv.x, inv.y, inv.z, inv.w};
#pragma unroll
            for (int qi = 0; qi < 4; ++qi) {
                int q = qbase + q0 + qi;
                float4 svv = *reinterpret_cast<const float4*>(
                    &svt[(size_t)q * N_BANK + j0 + j0l]);
                float s[4] = {svv.x, svv.y, svv.z, svv.w};
#pragma unroll
                for (int ji = 0; ji < 4; ++ji)
                    Ss[q0 + qi][j0l + ji] = 0.5f * (acc[qi][ji] * iv[ji]) + 0.5f * s[ji];
            }
        } else {
#pragma unroll
            for (int qi = 0; qi < 4; ++qi) {
                int q = qbase + q0 + qi;
#pragma unroll
                for (int ji = 0; ji < 4; ++ji) {
                    int jg = j0 + j0l + ji;
                    float s = -INFINITY;
                    if (jg < N_BANK)
                        s = 0.5f * (acc[qi][ji] * inorm[jg]) + 0.5f * svt[(size_t)q * N_BANK + jg];
                    Ss[q0 + qi][j0l + ji] = s;
                }
            }
        }
        __syncthreads();
        if (t < FBT) {
#pragma unroll 1
            for (int jj = 0; jj < FJT; ++jj) {
                int jg = j0 + jj;
                if (jg >= N_BANK) break;
                float s = Ss[t][jj];
                if (s > sc[K16 - 1] || (s == sc[K16 - 1] && jg < id[K16 - 1])) {
                    float cs = s; int ci = jg;
#pragma unroll
                    for (int i = 0; i < K16; ++i) {
                        bool bt2 = (cs > sc[i]) || (cs == sc[i] && ci < id[i]);
                        float ts = sc[i]; int ti = id[i];
                        if (bt2) { sc[i] = cs; id[i] = ci; cs = ts; ci = ti; }
                    }
                }
            }
        }
    }
    if (t < FBT) {
        int q = qbase + t;
        size_t base = ((size_t)q * FNS + slice) * K16;
#pragma unroll
        for (int i = 0; i < K16; ++i) { psc[base + i] = sc[i]; pid[base + i] = id[i]; }
    }
}

__global__ __launch_bounds__(256)
void fb_merge_kernel(const float* __restrict__ psc,
                     const int* __restrict__ pid,
                     const float* __restrict__ bank,
                     float* __restrict__ out) {
    __shared__ unsigned long long keys[FNS * K16];
    __shared__ unsigned long long wred[4];
    __shared__ int win[K16];
    int b = blockIdx.x, t = threadIdx.x;
    for (int i = t; i < FNS * K16; i += 256) {
        float s = psc[(size_t)b * FNS * K16 + i];
        unsigned int u = __float_as_uint(s);
        u ^= (u & 0x80000000u) ? 0xFFFFFFFFu : 0x80000000u;
        unsigned int iv = ~(unsigned int)pid[(size_t)b * FNS * K16 + i];
        keys[i] = ((unsigned long long)u << 32) | iv;
    }
    __syncthreads();
    for (int r = 0; r < K16; ++r) {
        unsigned long long best = 0ull;
        for (int i = t; i < FNS * K16; i += 256) best = umax64(best, keys[i]);
#pragma unroll
        for (int off = 32; off > 0; off >>= 1) best = umax64(best, shfl_down_u64(best, off));
        if ((t & 63) == 0) wred[t >> 6] = best;
        __syncthreads();
        unsigned long long w = umax64(umax64(wred[0], wred[1]), umax64(wred[2], wred[3]));
        if (t == 0) win[r] = (int)(~(unsigned int)w);
        for (int i = t; i < FNS * K16; i += 256)
            if (keys[i] == w) keys[i] = 0ull;
        __syncthreads();
    }
    if (t < K16)
        out[(size_t)B_Q * K16 * D_DIM + (size_t)b * K16 + t] = (float)win[t];
    const float4* bank4 = reinterpret_cast<const float4*>(bank);
    float4* out4 = reinterpret_cast<float4*>(out);
    for (int u = t; u < K16 * 64; u += 256) {
        int r = u >> 6, c = u & 63;
        out4[((size_t)b * K16 + r) * 64 + c] = bank4[(size_t)win[r] * 64 + c];
    }
}

// ---------------- launcher ----------------
extern "C" void kernel_launch(void* const* d_in, const int* in_sizes, int n_in,
                              void* d_out, int out_size, void* d_ws, size_t ws_size,
                              hipStream_t stream) {
    const float* z_ego = (const float*)d_in[0];
    const float* bank  = (const float*)d_in[1];
    const float* svt   = (const float*)d_in[2];
    const float* W     = (const float*)d_in[3];
    float* out = (float*)d_out;
    char* ws = (char*)d_ws;

    if (ws_size >= WS_NEED) {
        float* qn             = (float*)(ws + OFF_QN);
        unsigned short* qnt   = (unsigned short*)(ws + OFF_QNT);
        float* inorm          = (float*)(ws + OFF_INORM);
        float* psc            = (float*)(ws + OFF_PSC);
        int*   pid            = (int*)(ws + OFF_PID);
        unsigned short* bankt = (unsigned short*)(ws + OFF_BANKN);

        qn_prep_kernel<<<B_Q, 256, 0, stream>>>(z_ego, W, qn, qnt);
        inorm_kernel<<<(N_BANK + 3) / 4, 256, 0, stream>>>(bank, inorm);
        convert_kernel<<<NCHUNK, 256, 0, stream>>>(bank, inorm, bankt);
        score_mfma_kernel<<<NSLICE * 8, 256, 0, stream>>>(qnt, bankt, svt, psc, pid);
        select_rescore_kernel<<<B_Q, 256, 0, stream>>>(psc, pid, qn, inorm, bank, svt, out);
    } else {
        float* qn    = (float*)(ws + 0);
        float* inorm = (float*)(ws + FB_OFF_INORM);
        float* psc   = (float*)(ws + FB_OFF_PSC);
        int*   pid   = (int*)(ws + FB_OFF_PID);
        fb_qn_kernel<<<B_Q, 256, 0, stream>>>(z_ego, W, qn);
        inorm_kernel<<<(N_BANK + 3) / 4, 256, 0, stream>>>(bank, inorm);
        dim3 grid(FNS, B_Q / FBT);
        fb_score_topk_kernel<<<grid, 256, 0, stream>>>(qn, bank, svt, inorm, psc, pid);
        fb_merge_kernel<<<B_Q, 256, 0, stream>>>(psc, pid, bank, out);
    }
}

// Round 3
// 806.773 us; speedup vs baseline: 3.4006x; 1.4936x over previous
//
#include <hip/hip_runtime.h>
#include <math.h>
#include <stdint.h>

#define B_Q    512
#define N_BANK 100000
#define D_DIM  256
#define K16    16

// ---------------- MFMA path constants ----------------
#define NSL    128                          // j-slices for screen/collect
#define NCHUNK 1563                         // ceil(100000/64)
#define TROW   264                          // bf16 elems per padded row (256 + 8 pad)
#define CHUNK_USHORT (64 * TROW)            // 16896
#define CHUNK_BYTES  (CHUNK_USHORT * 2)     // 33792
#define POOL_PER_Q (NSL * 64)               // 8192 bucket-maxima per query
#define MARGIN 5e-3f                        // >= 2*eps_screen (worst-case bf16 dot bound)
#define CAP    1024

// ws layout (bytes)
#define OFF_QN     0                        // fp32 qn: 512KB
#define OFF_QNT    0x80000                  // bf16 tiled qn: 270336
#define OFF_INORM  0x100000                 // fp32 inorm: 400000
#define OFF_TH     0x170000                 // fp32 th[512]
#define OFF_CNT    0x171000                 // int cnt[512]
#define OFF_CAND   0x180000                 // int cand[512][1024] = 2MB
#define OFF_POOL   0x400000                 // fp32 pool[512][8192] = 16MB
#define OFF_BANKT  0x1400000                // bf16 tiled bank: 1563*33792
#define WS_NEED    ((size_t)OFF_BANKT + (size_t)NCHUNK * CHUNK_BYTES)

// fallback path ws layout
#define FB_OFF_INORM (B_Q * D_DIM * 4)
#define FB_OFF_PSC   (1024 * 1024)
#define FB_OFF_PID   (FB_OFF_PSC + B_Q * 128 * K16 * 4)

typedef __attribute__((ext_vector_type(8))) short short8;
typedef __attribute__((ext_vector_type(4))) float floatx4;

// ---------------- helpers ----------------
__device__ inline unsigned short f2bf(float x) {   // RNE fp32 -> bf16
    unsigned int u = __float_as_uint(x);
    unsigned int r = (u + 0x7FFFu + ((u >> 16) & 1u)) >> 16;
    return (unsigned short)r;
}
__device__ inline unsigned long long pack_key(float s, int idx) {
    unsigned int u = __float_as_uint(s);
    u ^= (u & 0x80000000u) ? 0xFFFFFFFFu : 0x80000000u;  // order-preserving
    return ((unsigned long long)u << 32) | (unsigned int)(~(unsigned int)idx);
}
__device__ inline int key_idx(unsigned long long k) {
    return (int)(~(unsigned int)(k & 0xFFFFFFFFull));
}
__device__ inline unsigned long long shfl_down_u64(unsigned long long x, int off) {
    unsigned int lo = (unsigned int)x;
    unsigned int hi = (unsigned int)(x >> 32);
    lo = __shfl_down(lo, off, 64);
    hi = __shfl_down(hi, off, 64);
    return ((unsigned long long)hi << 32) | lo;
}
__device__ inline unsigned long long umax64(unsigned long long a, unsigned long long b) {
    return a > b ? a : b;
}

// ================= MFMA PATH =================

// qn = normalize(z_ego @ W^T) fp32, plus bf16 padded-tiled copy
__global__ void qn_prep_kernel(const float* __restrict__ z_ego,
                               const float* __restrict__ W,
                               float* __restrict__ qn,
                               unsigned short* __restrict__ qnt) {
    __shared__ float zs[D_DIM];
    __shared__ float red[4];
    int b = blockIdx.x;
    int t = threadIdx.x;
    zs[t] = z_ego[b * D_DIM + t];
    __syncthreads();
    const float4* W4 = reinterpret_cast<const float4*>(W + (size_t)t * D_DIM);
    float acc = 0.f;
#pragma unroll 8
    for (int u = 0; u < 64; ++u) {
        float4 w = W4[u];
        acc += w.x * zs[u * 4 + 0];
        acc += w.y * zs[u * 4 + 1];
        acc += w.z * zs[u * 4 + 2];
        acc += w.w * zs[u * 4 + 3];
    }
    float ss = acc * acc;
#pragma unroll
    for (int off = 32; off > 0; off >>= 1) ss += __shfl_down(ss, off, 64);
    if ((t & 63) == 0) red[t >> 6] = ss;
    __syncthreads();
    float tot = red[0] + red[1] + red[2] + red[3];
    float n = fmaxf(sqrtf(tot), 1e-12f);
    float v = acc / n;
    qn[b * D_DIM + t] = v;
    qnt[(size_t)(b >> 6) * CHUNK_USHORT + (size_t)(b & 63) * TROW + t] = f2bf(v);
}

// fused: row norms + bf16 normalized tiled bank
__global__ __launch_bounds__(256)
void prep_bank_kernel(const float* __restrict__ bank,
                      float* __restrict__ inorm,
                      unsigned short* __restrict__ bankt) {
    int c = blockIdx.x;
    int t = threadIdx.x, w = t >> 6, l = t & 63;
    unsigned short* dst = bankt + (size_t)c * CHUNK_USHORT;
#pragma unroll 1
    for (int rr = 0; rr < 16; ++rr) {
        int row = w * 16 + rr;
        int jg = c * 64 + row;
        ushort4 o = {0, 0, 0, 0};
        if (jg < N_BANK) {
            float4 v = *reinterpret_cast<const float4*>(bank + (size_t)jg * D_DIM + l * 4);
            float ss = v.x * v.x + v.y * v.y + v.z * v.z + v.w * v.w;
#pragma unroll
            for (int off = 1; off < 64; off <<= 1) ss += __shfl_xor(ss, off, 64);
            float inv = 1.0f / fmaxf(sqrtf(ss), 1e-12f);
            o.x = f2bf(v.x * inv); o.y = f2bf(v.y * inv);
            o.z = f2bf(v.z * inv); o.w = f2bf(v.w * inv);
            if (l == 0) inorm[jg] = inv;
        }
        *reinterpret_cast<ushort4*>(dst + (size_t)row * TROW + l * 4) = o;
    }
}

// screen pass: MFMA scores, per-thread-per-query running max into pool
__global__ __launch_bounds__(256, 4)
void screen_kernel(const unsigned short* __restrict__ qnt,
                   const unsigned short* __restrict__ bankt,
                   const float* __restrict__ svt,
                   float* __restrict__ pool) {
    __shared__ __align__(16) unsigned short Bs[CHUNK_USHORT];
    int t = threadIdx.x, w = t >> 6, l = t & 63;
    int lane16 = l & 15, quad = l >> 4;
    int qt0 = blockIdx.x & 15;          // 16 tiles of 32 queries
    int slice = blockIdx.x >> 4;
    int qbase = qt0 * 32;

    short8 afrag[2][8];
    {
        const unsigned short* abase = qnt + (size_t)(qt0 >> 1) * CHUNK_USHORT
                                          + (size_t)((qt0 & 1) * 32) * TROW;
#pragma unroll
        for (int s = 0; s < 2; ++s)
#pragma unroll
            for (int k = 0; k < 8; ++k)
                afrag[s][k] = *reinterpret_cast<const short8*>(
                    abase + (size_t)(16 * s + lane16) * TROW + k * 32 + quad * 8);
    }

    float vmax[2][4];
#pragma unroll
    for (int s = 0; s < 2; ++s)
#pragma unroll
        for (int r = 0; r < 4; ++r) vmax[s][r] = -INFINITY;

    for (int c = slice; c < NCHUNK; c += NSL) {
        __syncthreads();
        {
            const char* src = reinterpret_cast<const char*>(bankt) + (size_t)c * CHUNK_BYTES;
            char* dstc = reinterpret_cast<char*>(Bs);
#pragma unroll
            for (int i = 0; i < 9; ++i) {
                int off = t * 16 + i * 4096;
                if (off < CHUNK_BYTES)
                    *reinterpret_cast<uint4*>(dstc + off) =
                        *reinterpret_cast<const uint4*>(src + off);
            }
        }
        int j0 = c * 64;
        int jglob = j0 + 16 * w + lane16;
        bool inb = jglob < N_BANK;
        float sv[2][4];
#pragma unroll
        for (int s = 0; s < 2; ++s)
#pragma unroll
            for (int r = 0; r < 4; ++r) {
                int q = qbase + 16 * s + 4 * quad + r;
                sv[s][r] = inb ? svt[(size_t)q * N_BANK + jglob] : 0.f;
            }
        __syncthreads();

        floatx4 acc[2];
#pragma unroll
        for (int s = 0; s < 2; ++s) acc[s] = (floatx4){0.f, 0.f, 0.f, 0.f};
#pragma unroll
        for (int k = 0; k < 8; ++k) {
            short8 bfrag = *reinterpret_cast<const short8*>(
                Bs + (size_t)(16 * w + lane16) * TROW + k * 32 + quad * 8);
#pragma unroll
            for (int s = 0; s < 2; ++s)
                acc[s] = __builtin_amdgcn_mfma_f32_16x16x32_bf16(afrag[s][k], bfrag, acc[s], 0, 0, 0);
        }
#pragma unroll
        for (int s = 0; s < 2; ++s)
#pragma unroll
            for (int r = 0; r < 4; ++r) {
                float score = 0.5f * acc[s][r] + 0.5f * sv[s][r];
                score = inb ? score : -INFINITY;
                vmax[s][r] = fmaxf(vmax[s][r], score);
            }
    }

#pragma unroll
    for (int s = 0; s < 2; ++s)
#pragma unroll
        for (int r = 0; r < 4; ++r) {
            int q = qbase + 16 * s + 4 * quad + r;
            pool[((size_t)q * NSL + slice) * 64 + w * 16 + lane16] = vmax[s][r];
        }
}

// per-query: 16th-largest of pool - margin -> th; zero cnt
__global__ __launch_bounds__(256)
void thresh_kernel(const float* __restrict__ pool,
                   float* __restrict__ th,
                   int* __restrict__ cnt) {
    __shared__ float buf[POOL_PER_Q];    // 32 KB
    __shared__ float red[4];
    int q = blockIdx.x, t = threadIdx.x;
    int w = t >> 6;
    for (int i = t; i < POOL_PER_Q; i += 256) buf[i] = pool[(size_t)q * POOL_PER_Q + i];
    __syncthreads();
    float s16 = -INFINITY;
    for (int r = 0; r < K16; ++r) {
        float m = -INFINITY;
        for (int i = t; i < POOL_PER_Q; i += 256) m = fmaxf(m, buf[i]);
#pragma unroll
        for (int off = 32; off > 0; off >>= 1) m = fmaxf(m, __shfl_down(m, off, 64));
        if ((t & 63) == 0) red[w] = m;
        __syncthreads();
        m = fmaxf(fmaxf(red[0], red[1]), fmaxf(red[2], red[3]));
        if (r == K16 - 1) s16 = m;
        for (int i = t; i < POOL_PER_Q; i += 256)
            if (buf[i] == m) buf[i] = -INFINITY;
        __syncthreads();
    }
    if (t == 0) { th[q] = s16 - MARGIN; cnt[q] = 0; }
}

// collect pass: recompute scores (bitwise-identical), gather j with score >= th[q]
__global__ __launch_bounds__(256, 4)
void collect_kernel(const unsigned short* __restrict__ qnt,
                    const unsigned short* __restrict__ bankt,
                    const float* __restrict__ svt,
                    const float* __restrict__ th,
                    int* __restrict__ cnt,
                    int* __restrict__ cand) {
    __shared__ __align__(16) unsigned short Bs[CHUNK_USHORT];
    int t = threadIdx.x, w = t >> 6, l = t & 63;
    int lane16 = l & 15, quad = l >> 4;
    int qt0 = blockIdx.x & 15;
    int slice = blockIdx.x >> 4;
    int qbase = qt0 * 32;

    short8 afrag[2][8];
    {
        const unsigned short* abase = qnt + (size_t)(qt0 >> 1) * CHUNK_USHORT
                                          + (size_t)((qt0 & 1) * 32) * TROW;
#pragma unroll
        for (int s = 0; s < 2; ++s)
#pragma unroll
            for (int k = 0; k < 8; ++k)
                afrag[s][k] = *reinterpret_cast<const short8*>(
                    abase + (size_t)(16 * s + lane16) * TROW + k * 32 + quad * 8);
    }
    float thr[2][4];
#pragma unroll
    for (int s = 0; s < 2; ++s)
#pragma unroll
        for (int r = 0; r < 4; ++r)
            thr[s][r] = th[qbase + 16 * s + 4 * quad + r];

    for (int c = slice; c < NCHUNK; c += NSL) {
        __syncthreads();
        {
            const char* src = reinterpret_cast<const char*>(bankt) + (size_t)c * CHUNK_BYTES;
            char* dstc = reinterpret_cast<char*>(Bs);
#pragma unroll
            for (int i = 0; i < 9; ++i) {
                int off = t * 16 + i * 4096;
                if (off < CHUNK_BYTES)
                    *reinterpret_cast<uint4*>(dstc + off) =
                        *reinterpret_cast<const uint4*>(src + off);
            }
        }
        int j0 = c * 64;
        int jglob = j0 + 16 * w + lane16;
        bool inb = jglob < N_BANK;
        float sv[2][4];
#pragma unroll
        for (int s = 0; s < 2; ++s)
#pragma unroll
            for (int r = 0; r < 4; ++r) {
                int q = qbase + 16 * s + 4 * quad + r;
                sv[s][r] = inb ? svt[(size_t)q * N_BANK + jglob] : 0.f;
            }
        __syncthreads();

        floatx4 acc[2];
#pragma unroll
        for (int s = 0; s < 2; ++s) acc[s] = (floatx4){0.f, 0.f, 0.f, 0.f};
#pragma unroll
        for (int k = 0; k < 8; ++k) {
            short8 bfrag = *reinterpret_cast<const short8*>(
                Bs + (size_t)(16 * w + lane16) * TROW + k * 32 + quad * 8);
#pragma unroll
            for (int s = 0; s < 2; ++s)
                acc[s] = __builtin_amdgcn_mfma_f32_16x16x32_bf16(afrag[s][k], bfrag, acc[s], 0, 0, 0);
        }
#pragma unroll
        for (int s = 0; s < 2; ++s)
#pragma unroll
            for (int r = 0; r < 4; ++r) {
                float score = 0.5f * acc[s][r] + 0.5f * sv[s][r];
                if (inb && score >= thr[s][r]) {
                    int q = qbase + 16 * s + 4 * quad + r;
                    int p = atomicAdd(&cnt[q], 1);
                    if (p < CAP) cand[(size_t)q * CAP + p] = jglob;
                }
            }
    }
}

// exact fp32 rescore of survivors -> top-16 -> gather
__global__ __launch_bounds__(256)
void rescore_kernel(const int* __restrict__ cand,
                    const int* __restrict__ cnt,
                    const float* __restrict__ qn,
                    const float* __restrict__ inorm,
                    const float* __restrict__ bank,
                    const float* __restrict__ svt,
                    float* __restrict__ out) {
    __shared__ float qns[D_DIM];
    __shared__ int candL[CAP];
    __shared__ unsigned long long keys2[CAP];
    __shared__ unsigned long long wred[4];
    __shared__ int winI[K16];
    int b = blockIdx.x, t = threadIdx.x;
    int w = t >> 6, l = t & 63;

    qns[t] = qn[(size_t)b * D_DIM + t];
    int cq = cnt[b];
    if (cq > CAP) cq = CAP;
    for (int i = t; i < cq; i += 256) candL[i] = cand[(size_t)b * CAP + i];
    __syncthreads();

    const float4* bank4 = reinterpret_cast<const float4*>(bank);
    const float4* q4 = reinterpret_cast<const float4*>(qns);
    float4 qv = q4[l];
    for (int c = w; c < cq; c += 4) {
        int j = candL[c];
        float4 bv = bank4[(size_t)j * 64 + l];
        float d = qv.x * bv.x + qv.y * bv.y + qv.z * bv.z + qv.w * bv.w;
#pragma unroll
        for (int off = 32; off > 0; off >>= 1) d += __shfl_down(d, off, 64);
        if (l == 0) {
            float score = 0.5f * (d * inorm[j]) + 0.5f * svt[(size_t)b * N_BANK + j];
            keys2[c] = pack_key(score, j);
        }
    }
    __syncthreads();

    for (int r = 0; r < K16; ++r) {
        unsigned long long best = 0ull;
        for (int i = t; i < cq; i += 256) best = umax64(best, keys2[i]);
#pragma unroll
        for (int off = 32; off > 0; off >>= 1) best = umax64(best, shfl_down_u64(best, off));
        if (l == 0) wred[w] = best;
        __syncthreads();
        unsigned long long W = umax64(umax64(wred[0], wred[1]), umax64(wred[2], wred[3]));
        if (t == 0) winI[r] = key_idx(W);
        for (int i = t; i < cq; i += 256)
            if (keys2[i] == W) keys2[i] = 0ull;
        __syncthreads();
    }

    if (t < K16)
        out[(size_t)B_Q * K16 * D_DIM + (size_t)b * K16 + t] = (float)winI[t];
    float4* out4 = reinterpret_cast<float4*>(out);
    for (int u = t; u < K16 * 64; u += 256) {
        int r = u >> 6, cc = u & 63;
        out4[((size_t)b * K16 + r) * 64 + cc] = bank4[(size_t)winI[r] * 64 + cc];
    }
}

// ================= FALLBACK (verified round-1) PATH =================
#define FBT 64
#define FJT 64
#define FKC 64
#define FNS 128
#define FNC ((N_BANK + FJT - 1) / FJT)

__global__ void inorm_kernel(const float* __restrict__ bank,
                             float* __restrict__ inorm) {
    int w = threadIdx.x >> 6;
    int lane = threadIdx.x & 63;
    int j = blockIdx.x * 4 + w;
    if (j >= N_BANK) return;
    const float4* r4 = reinterpret_cast<const float4*>(bank + (size_t)j * D_DIM);
    float4 v = r4[lane];
    float ss = v.x * v.x + v.y * v.y + v.z * v.z + v.w * v.w;
#pragma unroll
    for (int off = 32; off > 0; off >>= 1) ss += __shfl_down(ss, off, 64);
    if (lane == 0) inorm[j] = 1.0f / fmaxf(sqrtf(ss), 1e-12f);
}

__global__ void fb_qn_kernel(const float* __restrict__ z_ego,
                             const float* __restrict__ W,
                             float* __restrict__ qn) {
    __shared__ float zs[D_DIM];
    __shared__ float red[4];
    int b = blockIdx.x;
    int t = threadIdx.x;
    zs[t] = z_ego[b * D_DIM + t];
    __syncthreads();
    const float4* W4 = reinterpret_cast<const float4*>(W + (size_t)t * D_DIM);
    float acc = 0.f;
#pragma unroll 8
    for (int u = 0; u < 64; ++u) {
        float4 w = W4[u];
        acc += w.x * zs[u * 4 + 0]; acc += w.y * zs[u * 4 + 1];
        acc += w.z * zs[u * 4 + 2]; acc += w.w * zs[u * 4 + 3];
    }
    float ss = acc * acc;
#pragma unroll
    for (int off = 32; off > 0; off >>= 1) ss += __shfl_down(ss, off, 64);
    if ((t & 63) == 0) red[t >> 6] = ss;
    __syncthreads();
    float tot = red[0] + red[1] + red[2] + red[3];
    qn[b * D_DIM + t] = acc / fmaxf(sqrtf(tot), 1e-12f);
}

__global__ __launch_bounds__(256)
void fb_score_topk_kernel(const float* __restrict__ qn,
                          const float* __restrict__ bank,
                          const float* __restrict__ svt,
                          const float* __restrict__ inorm,
                          float* __restrict__ psc,
                          int* __restrict__ pid) {
    __shared__ float As[FKC][FBT];
    __shared__ float Bsh[FKC][FJT];
    __shared__ float Ss[FBT][FJT + 1];
    int slice = blockIdx.x;
    int qbase = blockIdx.y * FBT;
    int t = threadIdx.x;
    int tq = t >> 4, tj = t & 15;
    int q0 = tq * 4, j0l = tj * 4;
    float sc[K16]; int id[K16];
#pragma unroll
    for (int i = 0; i < K16; ++i) { sc[i] = -INFINITY; id[i] = 0x7fffffff; }
    for (int c = slice; c < FNC; c += FNS) {
        int j0 = c * FJT;
        float acc[4][4];
#pragma unroll
        for (int a = 0; a < 4; ++a)
#pragma unroll
            for (int b2 = 0; b2 < 4; ++b2) acc[a][b2] = 0.f;
        for (int kc = 0; kc < D_DIM; kc += FKC) {
            __syncthreads();
#pragma unroll
            for (int r = 0; r < 4; ++r) {
                int idx = t + 256 * r;
                int q = idx & 63, kv = idx >> 6;
                float4 v = *reinterpret_cast<const float4*>(
                    &qn[(size_t)(qbase + q) * D_DIM + kc + kv * 4]);
                As[kv * 4 + 0][q] = v.x; As[kv * 4 + 1][q] = v.y;
                As[kv * 4 + 2][q] = v.z; As[kv * 4 + 3][q] = v.w;
            }
#pragma unroll
            for (int r = 0; r < 4; ++r) {
                int idx = t + 256 * r;
                int j = idx & 63, kv = idx >> 6;
                int jg = j0 + j;
                float4 v = make_float4(0.f, 0.f, 0.f, 0.f);
                if (jg < N_BANK)
                    v = *reinterpret_cast<const float4*>(
                        &bank[(size_t)jg * D_DIM + kc + kv * 4]);
                Bsh[kv * 4 + 0][j] = v.x; Bsh[kv * 4 + 1][j] = v.y;
                Bsh[kv * 4 + 2][j] = v.z; Bsh[kv * 4 + 3][j] = v.w;
            }
            __syncthreads();
#pragma unroll
            for (int k = 0; k < FKC; ++k) {
                float4 av = *reinterpret_cast<const float4*>(&As[k][q0]);
                float4 bv = *reinterpret_cast<const float4*>(&Bsh[k][j0l]);
                float a[4] = {av.x, av.y, av.z, av.w};
                float bb[4] = {bv.x, bv.y, bv.z, bv.w};
#pragma unroll
                for (int qi = 0; qi < 4; ++qi)
#pragma unroll
                    for (int ji = 0; ji < 4; ++ji) acc[qi][ji] += a[qi] * bb[ji];
            }
        }
        bool full = (j0 + FJT <= N_BANK);
        if (full) {
            float4 inv = *reinterpret_cast<const float4*>(&inorm[j0 + j0l]);
            float iv[4] = {inv.x, inv.y, inv.z, inv.w};
#pragma unroll
            for (int qi = 0; qi < 4; ++qi) {
                int q = qbase + q0 + qi;
                float4 svv = *reinterpret_cast<const float4*>(
                    &svt[(size_t)q * N_BANK + j0 + j0l]);
                float s[4] = {svv.x, svv.y, svv.z, svv.w};
#pragma unroll
                for (int ji = 0; ji < 4; ++ji)
                    Ss[q0 + qi][j0l + ji] = 0.5f * (acc[qi][ji] * iv[ji]) + 0.5f * s[ji];
            }
        } else {
#pragma unroll
            for (int qi = 0; qi < 4; ++qi) {
                int q = qbase + q0 + qi;
#pragma unroll
                for (int ji = 0; ji < 4; ++ji) {
                    int jg = j0 + j0l + ji;
                    float s = -INFINITY;
                    if (jg < N_BANK)
                        s = 0.5f * (acc[qi][ji] * inorm[jg]) + 0.5f * svt[(size_t)q * N_BANK + jg];
                    Ss[q0 + qi][j0l + ji] = s;
                }
            }
        }
        __syncthreads();
        if (t < FBT) {
#pragma unroll 1
            for (int jj = 0; jj < FJT; ++jj) {
                int jg = j0 + jj;
                if (jg >= N_BANK) break;
                float s = Ss[t][jj];
                if (s > sc[K16 - 1] || (s == sc[K16 - 1] && jg < id[K16 - 1])) {
                    float cs = s; int ci = jg;
#pragma unroll
                    for (int i = 0; i < K16; ++i) {
                        bool bt2 = (cs > sc[i]) || (cs == sc[i] && ci < id[i]);
                        float ts = sc[i]; int ti = id[i];
                        if (bt2) { sc[i] = cs; id[i] = ci; cs = ts; ci = ti; }
                    }
                }
            }
        }
    }
    if (t < FBT) {
        int q = qbase + t;
        size_t base = ((size_t)q * FNS + slice) * K16;
#pragma unroll
        for (int i = 0; i < K16; ++i) { psc[base + i] = sc[i]; pid[base + i] = id[i]; }
    }
}

__global__ __launch_bounds__(256)
void fb_merge_kernel(const float* __restrict__ psc,
                     const int* __restrict__ pid,
                     const float* __restrict__ bank,
                     float* __restrict__ out) {
    __shared__ unsigned long long keys[FNS * K16];
    __shared__ unsigned long long wred[4];
    __shared__ int win[K16];
    int b = blockIdx.x, t = threadIdx.x;
    for (int i = t; i < FNS * K16; i += 256) {
        float s = psc[(size_t)b * FNS * K16 + i];
        unsigned int u = __float_as_uint(s);
        u ^= (u & 0x80000000u) ? 0xFFFFFFFFu : 0x80000000u;
        unsigned int iv = ~(unsigned int)pid[(size_t)b * FNS * K16 + i];
        keys[i] = ((unsigned long long)u << 32) | iv;
    }
    __syncthreads();
    for (int r = 0; r < K16; ++r) {
        unsigned long long best = 0ull;
        for (int i = t; i < FNS * K16; i += 256) best = umax64(best, keys[i]);
#pragma unroll
        for (int off = 32; off > 0; off >>= 1) best = umax64(best, shfl_down_u64(best, off));
        if ((t & 63) == 0) wred[t >> 6] = best;
        __syncthreads();
        unsigned long long w = umax64(umax64(wred[0], wred[1]), umax64(wred[2], wred[3]));
        if (t == 0) win[r] = (int)(~(unsigned int)w);
        for (int i = t; i < FNS * K16; i += 256)
            if (keys[i] == w) keys[i] = 0ull;
        __syncthreads();
    }
    if (t < K16)
        out[(size_t)B_Q * K16 * D_DIM + (size_t)b * K16 + t] = (float)win[t];
    const float4* bank4 = reinterpret_cast<const float4*>(bank);
    float4* out4 = reinterpret_cast<float4*>(out);
    for (int u = t; u < K16 * 64; u += 256) {
        int r = u >> 6, c = u & 63;
        out4[((size_t)b * K16 + r) * 64 + c] = bank4[(size_t)win[r] * 64 + c];
    }
}

// ---------------- launcher ----------------
extern "C" void kernel_launch(void* const* d_in, const int* in_sizes, int n_in,
                              void* d_out, int out_size, void* d_ws, size_t ws_size,
                              hipStream_t stream) {
    const float* z_ego = (const float*)d_in[0];
    const float* bank  = (const float*)d_in[1];
    const float* svt   = (const float*)d_in[2];
    const float* W     = (const float*)d_in[3];
    float* out = (float*)d_out;
    char* ws = (char*)d_ws;

    if (ws_size >= WS_NEED) {
        float* qn             = (float*)(ws + OFF_QN);
        unsigned short* qnt   = (unsigned short*)(ws + OFF_QNT);
        float* inorm          = (float*)(ws + OFF_INORM);
        float* th             = (float*)(ws + OFF_TH);
        int*   cnt            = (int*)(ws + OFF_CNT);
        int*   cand           = (int*)(ws + OFF_CAND);
        float* pool           = (float*)(ws + OFF_POOL);
        unsigned short* bankt = (unsigned short*)(ws + OFF_BANKT);

        qn_prep_kernel<<<B_Q, 256, 0, stream>>>(z_ego, W, qn, qnt);
        prep_bank_kernel<<<NCHUNK, 256, 0, stream>>>(bank, inorm, bankt);
        screen_kernel<<<NSL * 16, 256, 0, stream>>>(qnt, bankt, svt, pool);
        thresh_kernel<<<B_Q, 256, 0, stream>>>(pool, th, cnt);
        collect_kernel<<<NSL * 16, 256, 0, stream>>>(qnt, bankt, svt, th, cnt, cand);
        rescore_kernel<<<B_Q, 256, 0, stream>>>(cand, cnt, qn, inorm, bank, svt, out);
    } else {
        float* qn    = (float*)(ws + 0);
        float* inorm = (float*)(ws + FB_OFF_INORM);
        float* psc   = (float*)(ws + FB_OFF_PSC);
        int*   pid   = (int*)(ws + FB_OFF_PID);
        fb_qn_kernel<<<B_Q, 256, 0, stream>>>(z_ego, W, qn);
        inorm_kernel<<<(N_BANK + 3) / 4, 256, 0, stream>>>(bank, inorm);
        dim3 grid(FNS, B_Q / FBT);
        fb_score_topk_kernel<<<grid, 256, 0, stream>>>(qn, bank, svt, inorm, psc, pid);
        fb_merge_kernel<<<B_Q, 256, 0, stream>>>(psc, pid, bank, out);
    }
}

// Round 4
// 729.823 us; speedup vs baseline: 3.7591x; 1.1054x over previous
//
#include <hip/hip_runtime.h>
#include <math.h>
#include <stdint.h>

#define B_Q    512
#define N_BANK 100000
#define D_DIM  256
#define K16    16

// ---------------- MFMA path constants ----------------
#define NSL    128                          // j-slices for screen
#define NCHUNK 1563                         // ceil(100000/64)
#define TROW   264                          // bf16 elems per padded row (256 + 8 pad)
#define CHUNK_USHORT (64 * TROW)            // 16896
#define CHUNK_BYTES  (CHUNK_USHORT * 2)     // 33792
#define NGRP   6250                         // 100000 / 16 j-groups per query
#define GSTRIDE 6272                        // padded group row stride (floats)
#define MARGIN 5e-3f                        // >= 2*eps_screen (worst-case bf16 dot bound)
#define CAPG   384                          // max surviving groups per query (exp ~30)

// ws layout (bytes)
#define OFF_QN     0                        // fp32 qn: 512KB
#define OFF_QNT    0x80000                  // bf16 tiled qn: 270336
#define OFF_INORM  0x100000                 // fp32 inorm: 400000
#define OFF_TH     0x170000                 // fp32 th[512]
#define OFF_GMAX   0x400000                 // fp32 gmax[512][6272] = 12.85MB (ends < 0x1400000)
#define OFF_BANKT  0x1400000                // bf16 tiled bank: 1563*33792
#define WS_NEED    ((size_t)OFF_BANKT + (size_t)NCHUNK * CHUNK_BYTES)

// fallback path ws layout
#define FB_OFF_INORM (B_Q * D_DIM * 4)
#define FB_OFF_PSC   (1024 * 1024)
#define FB_OFF_PID   (FB_OFF_PSC + B_Q * 128 * K16 * 4)

typedef __attribute__((ext_vector_type(8))) short short8;
typedef __attribute__((ext_vector_type(4))) float floatx4;

// ---------------- helpers ----------------
__device__ inline unsigned short f2bf(float x) {   // RNE fp32 -> bf16
    unsigned int u = __float_as_uint(x);
    unsigned int r = (u + 0x7FFFu + ((u >> 16) & 1u)) >> 16;
    return (unsigned short)r;
}
__device__ inline unsigned long long pack_key(float s, int idx) {
    unsigned int u = __float_as_uint(s);
    u ^= (u & 0x80000000u) ? 0xFFFFFFFFu : 0x80000000u;  // order-preserving
    return ((unsigned long long)u << 32) | (unsigned int)(~(unsigned int)idx);
}
__device__ inline int key_idx(unsigned long long k) {
    return (int)(~(unsigned int)(k & 0xFFFFFFFFull));
}
__device__ inline unsigned long long shfl_down_u64(unsigned long long x, int off) {
    unsigned int lo = (unsigned int)x;
    unsigned int hi = (unsigned int)(x >> 32);
    lo = __shfl_down(lo, off, 64);
    hi = __shfl_down(hi, off, 64);
    return ((unsigned long long)hi << 32) | lo;
}
__device__ inline unsigned long long umax64(unsigned long long a, unsigned long long b) {
    return a > b ? a : b;
}

// ================= MFMA PATH =================

// qn = normalize(z_ego @ W^T) fp32, plus bf16 padded-tiled copy
__global__ void qn_prep_kernel(const float* __restrict__ z_ego,
                               const float* __restrict__ W,
                               float* __restrict__ qn,
                               unsigned short* __restrict__ qnt) {
    __shared__ float zs[D_DIM];
    __shared__ float red[4];
    int b = blockIdx.x;
    int t = threadIdx.x;
    zs[t] = z_ego[b * D_DIM + t];
    __syncthreads();
    const float4* W4 = reinterpret_cast<const float4*>(W + (size_t)t * D_DIM);
    float acc = 0.f;
#pragma unroll 8
    for (int u = 0; u < 64; ++u) {
        float4 w = W4[u];
        acc += w.x * zs[u * 4 + 0];
        acc += w.y * zs[u * 4 + 1];
        acc += w.z * zs[u * 4 + 2];
        acc += w.w * zs[u * 4 + 3];
    }
    float ss = acc * acc;
#pragma unroll
    for (int off = 32; off > 0; off >>= 1) ss += __shfl_down(ss, off, 64);
    if ((t & 63) == 0) red[t >> 6] = ss;
    __syncthreads();
    float tot = red[0] + red[1] + red[2] + red[3];
    float n = fmaxf(sqrtf(tot), 1e-12f);
    float v = acc / n;
    qn[b * D_DIM + t] = v;
    qnt[(size_t)(b >> 6) * CHUNK_USHORT + (size_t)(b & 63) * TROW + t] = f2bf(v);
}

// fused: row norms + bf16 normalized tiled bank
__global__ __launch_bounds__(256)
void prep_bank_kernel(const float* __restrict__ bank,
                      float* __restrict__ inorm,
                      unsigned short* __restrict__ bankt) {
    int c = blockIdx.x;
    int t = threadIdx.x, w = t >> 6, l = t & 63;
    unsigned short* dst = bankt + (size_t)c * CHUNK_USHORT;
#pragma unroll 1
    for (int rr = 0; rr < 16; ++rr) {
        int row = w * 16 + rr;
        int jg = c * 64 + row;
        ushort4 o = {0, 0, 0, 0};
        if (jg < N_BANK) {
            float4 v = *reinterpret_cast<const float4*>(bank + (size_t)jg * D_DIM + l * 4);
            float ss = v.x * v.x + v.y * v.y + v.z * v.z + v.w * v.w;
#pragma unroll
            for (int off = 1; off < 64; off <<= 1) ss += __shfl_xor(ss, off, 64);
            float inv = 1.0f / fmaxf(sqrtf(ss), 1e-12f);
            o.x = f2bf(v.x * inv); o.y = f2bf(v.y * inv);
            o.z = f2bf(v.z * inv); o.w = f2bf(v.w * inv);
            if (l == 0) inorm[jg] = inv;
        }
        *reinterpret_cast<ushort4*>(dst + (size_t)row * TROW + l * 4) = o;
    }
}

// screen: barrier-free, LDS-free MFMA scoring; emits per-(q, 16-j-group) maxima
__global__ __launch_bounds__(256, 4)
void screen2_kernel(const unsigned short* __restrict__ qnt,
                    const unsigned short* __restrict__ bankt,
                    const float* __restrict__ svt,
                    float* __restrict__ gmax) {
    int t = threadIdx.x, w = t >> 6, l = t & 63;
    int lane16 = l & 15, quad = l >> 4;
    int qt0 = blockIdx.x & 15;          // 16 tiles of 32 queries
    int slice = blockIdx.x >> 4;
    int qbase = qt0 * 32;

    short8 afrag[2][8];
    {
        const unsigned short* abase = qnt + (size_t)(qt0 >> 1) * CHUNK_USHORT
                                          + (size_t)((qt0 & 1) * 32) * TROW;
#pragma unroll
        for (int s = 0; s < 2; ++s)
#pragma unroll
            for (int k = 0; k < 8; ++k)
                afrag[s][k] = *reinterpret_cast<const short8*>(
                    abase + (size_t)(16 * s + lane16) * TROW + k * 32 + quad * 8);
    }

    for (int c = slice; c < NCHUNK; c += NSL) {
        int j0 = c * 64;
        int jglob = j0 + 16 * w + lane16;
        bool inb = jglob < N_BANK;
        const unsigned short* bbase = bankt + (size_t)c * CHUNK_USHORT
                                            + (size_t)(16 * w + lane16) * TROW + quad * 8;
        float sv[2][4];
#pragma unroll
        for (int s = 0; s < 2; ++s)
#pragma unroll
            for (int r = 0; r < 4; ++r) {
                int q = qbase + 16 * s + 4 * quad + r;
                sv[s][r] = inb ? svt[(size_t)q * N_BANK + jglob] : 0.f;
            }

        floatx4 acc[2];
        acc[0] = (floatx4){0.f, 0.f, 0.f, 0.f};
        acc[1] = (floatx4){0.f, 0.f, 0.f, 0.f};
#pragma unroll
        for (int k = 0; k < 8; ++k) {
            short8 bfrag = *reinterpret_cast<const short8*>(bbase + k * 32);
            acc[0] = __builtin_amdgcn_mfma_f32_16x16x32_bf16(afrag[0][k], bfrag, acc[0], 0, 0, 0);
            acc[1] = __builtin_amdgcn_mfma_f32_16x16x32_bf16(afrag[1][k], bfrag, acc[1], 0, 0, 0);
        }

        int g = c * 4 + w;
        bool doStore = (lane16 == 0) && (g < NGRP);
#pragma unroll
        for (int s = 0; s < 2; ++s)
#pragma unroll
            for (int r = 0; r < 4; ++r) {
                float score = inb ? (0.5f * acc[s][r] + 0.5f * sv[s][r]) : -INFINITY;
                // max over the 16 j's (lane16 bits 0..3)
                score = fmaxf(score, __shfl_xor(score, 1, 64));
                score = fmaxf(score, __shfl_xor(score, 2, 64));
                score = fmaxf(score, __shfl_xor(score, 4, 64));
                score = fmaxf(score, __shfl_xor(score, 8, 64));
                if (doStore) {
                    int q = qbase + 16 * s + 4 * quad + r;
                    gmax[(size_t)q * GSTRIDE + g] = score;
                }
            }
    }
}

// per-query: 16th-largest group-max - margin -> th
__global__ __launch_bounds__(256)
void gthresh_kernel(const float* __restrict__ gmax,
                    float* __restrict__ th) {
    __shared__ float buf[NGRP];    // 25 KB
    __shared__ float red[4];
    int q = blockIdx.x, t = threadIdx.x, w = t >> 6;
    for (int i = t; i < NGRP; i += 256) buf[i] = gmax[(size_t)q * GSTRIDE + i];
    __syncthreads();
    float s16 = -INFINITY;
    for (int r = 0; r < K16; ++r) {
        float m = -INFINITY;
        for (int i = t; i < NGRP; i += 256) m = fmaxf(m, buf[i]);
#pragma unroll
        for (int off = 32; off > 0; off >>= 1) m = fmaxf(m, __shfl_down(m, off, 64));
        if ((t & 63) == 0) red[w] = m;
        __syncthreads();
        m = fmaxf(fmaxf(red[0], red[1]), fmaxf(red[2], red[3]));
        if (r == K16 - 1) s16 = m;
        if (r < K16 - 1) {
            for (int i = t; i < NGRP; i += 256)
                if (buf[i] == m) buf[i] = -INFINITY;
        }
        __syncthreads();
    }
    if (t == 0) th[q] = s16 - MARGIN;
}

// per-query: collect groups >= th, exact fp32 rescore of members, top-16, gather
__global__ __launch_bounds__(256)
void grescore_kernel(const float* __restrict__ gmax,
                     const float* __restrict__ th,
                     const float* __restrict__ qn,
                     const float* __restrict__ inorm,
                     const float* __restrict__ bank,
                     const float* __restrict__ svt,
                     float* __restrict__ out) {
    __shared__ float qns[D_DIM];
    __shared__ int glist[CAPG];
    __shared__ unsigned long long keys2[CAPG * K16];   // 48 KB
    __shared__ unsigned long long wred[4];
    __shared__ int winI[K16];
    __shared__ int gcntS;
    int b = blockIdx.x, t = threadIdx.x;
    int w = t >> 6, l = t & 63;

    qns[t] = qn[(size_t)b * D_DIM + t];
    if (t == 0) gcntS = 0;
    __syncthreads();
    float thb = th[b];
    for (int g = t; g < NGRP; g += 256) {
        if (gmax[(size_t)b * GSTRIDE + g] >= thb) {
            int p = atomicAdd(&gcntS, 1);
            if (p < CAPG) glist[p] = g;
        }
    }
    __syncthreads();
    int ng = gcntS < CAPG ? gcntS : CAPG;
    int ncand = ng * K16;

    const float4* bank4 = reinterpret_cast<const float4*>(bank);
    float4 qv = reinterpret_cast<const float4*>(qns)[l];
    for (int ci = w; ci < ncand; ci += 4) {
        int j = glist[ci >> 4] * K16 + (ci & 15);
        float4 bv = bank4[(size_t)j * 64 + l];
        float d = qv.x * bv.x + qv.y * bv.y + qv.z * bv.z + qv.w * bv.w;
#pragma unroll
        for (int off = 32; off > 0; off >>= 1) d += __shfl_down(d, off, 64);
        if (l == 0) {
            float score = 0.5f * (d * inorm[j]) + 0.5f * svt[(size_t)b * N_BANK + j];
            keys2[ci] = pack_key(score, j);
        }
    }
    __syncthreads();

    for (int r = 0; r < K16; ++r) {
        unsigned long long best = 0ull;
        for (int i = t; i < ncand; i += 256) best = umax64(best, keys2[i]);
#pragma unroll
        for (int off = 32; off > 0; off >>= 1) best = umax64(best, shfl_down_u64(best, off));
        if (l == 0) wred[w] = best;
        __syncthreads();
        unsigned long long W = umax64(umax64(wred[0], wred[1]), umax64(wred[2], wred[3]));
        if (t == 0) winI[r] = key_idx(W);
        for (int i = t; i < ncand; i += 256)
            if (keys2[i] == W) keys2[i] = 0ull;
        __syncthreads();
    }

    if (t < K16)
        out[(size_t)B_Q * K16 * D_DIM + (size_t)b * K16 + t] = (float)winI[t];
    float4* out4 = reinterpret_cast<float4*>(out);
    for (int u = t; u < K16 * 64; u += 256) {
        int r = u >> 6, cc = u & 63;
        out4[((size_t)b * K16 + r) * 64 + cc] = bank4[(size_t)winI[r] * 64 + cc];
    }
}

// ================= FALLBACK (verified round-1) PATH =================
#define FBT 64
#define FJT 64
#define FKC 64
#define FNS 128
#define FNC ((N_BANK + FJT - 1) / FJT)

__global__ void inorm_kernel(const float* __restrict__ bank,
                             float* __restrict__ inorm) {
    int w = threadIdx.x >> 6;
    int lane = threadIdx.x & 63;
    int j = blockIdx.x * 4 + w;
    if (j >= N_BANK) return;
    const float4* r4 = reinterpret_cast<const float4*>(bank + (size_t)j * D_DIM);
    float4 v = r4[lane];
    float ss = v.x * v.x + v.y * v.y + v.z * v.z + v.w * v.w;
#pragma unroll
    for (int off = 32; off > 0; off >>= 1) ss += __shfl_down(ss, off, 64);
    if (lane == 0) inorm[j] = 1.0f / fmaxf(sqrtf(ss), 1e-12f);
}

__global__ void fb_qn_kernel(const float* __restrict__ z_ego,
                             const float* __restrict__ W,
                             float* __restrict__ qn) {
    __shared__ float zs[D_DIM];
    __shared__ float red[4];
    int b = blockIdx.x;
    int t = threadIdx.x;
    zs[t] = z_ego[b * D_DIM + t];
    __syncthreads();
    const float4* W4 = reinterpret_cast<const float4*>(W + (size_t)t * D_DIM);
    float acc = 0.f;
#pragma unroll 8
    for (int u = 0; u < 64; ++u) {
        float4 w = W4[u];
        acc += w.x * zs[u * 4 + 0]; acc += w.y * zs[u * 4 + 1];
        acc += w.z * zs[u * 4 + 2]; acc += w.w * zs[u * 4 + 3];
    }
    float ss = acc * acc;
#pragma unroll
    for (int off = 32; off > 0; off >>= 1) ss += __shfl_down(ss, off, 64);
    if ((t & 63) == 0) red[t >> 6] = ss;
    __syncthreads();
    float tot = red[0] + red[1] + red[2] + red[3];
    qn[b * D_DIM + t] = acc / fmaxf(sqrtf(tot), 1e-12f);
}

__global__ __launch_bounds__(256)
void fb_score_topk_kernel(const float* __restrict__ qn,
                          const float* __restrict__ bank,
                          const float* __restrict__ svt,
                          const float* __restrict__ inorm,
                          float* __restrict__ psc,
                          int* __restrict__ pid) {
    __shared__ float As[FKC][FBT];
    __shared__ float Bsh[FKC][FJT];
    __shared__ float Ss[FBT][FJT + 1];
    int slice = blockIdx.x;
    int qbase = blockIdx.y * FBT;
    int t = threadIdx.x;
    int tq = t >> 4, tj = t & 15;
    int q0 = tq * 4, j0l = tj * 4;
    float sc[K16]; int id[K16];
#pragma unroll
    for (int i = 0; i < K16; ++i) { sc[i] = -INFINITY; id[i] = 0x7fffffff; }
    for (int c = slice; c < FNC; c += FNS) {
        int j0 = c * FJT;
        float acc[4][4];
#pragma unroll
        for (int a = 0; a < 4; ++a)
#pragma unroll
            for (int b2 = 0; b2 < 4; ++b2) acc[a][b2] = 0.f;
        for (int kc = 0; kc < D_DIM; kc += FKC) {
            __syncthreads();
#pragma unroll
            for (int r = 0; r < 4; ++r) {
                int idx = t + 256 * r;
                int q = idx & 63, kv = idx >> 6;
                float4 v = *reinterpret_cast<const float4*>(
                    &qn[(size_t)(qbase + q) * D_DIM + kc + kv * 4]);
                As[kv * 4 + 0][q] = v.x; As[kv * 4 + 1][q] = v.y;
                As[kv * 4 + 2][q] = v.z; As[kv * 4 + 3][q] = v.w;
            }
#pragma unroll
            for (int r = 0; r < 4; ++r) {
                int idx = t + 256 * r;
                int j = idx & 63, kv = idx >> 6;
                int jg = j0 + j;
                float4 v = make_float4(0.f, 0.f, 0.f, 0.f);
                if (jg < N_BANK)
                    v = *reinterpret_cast<const float4*>(
                        &bank[(size_t)jg * D_DIM + kc + kv * 4]);
                Bsh[kv * 4 + 0][j] = v.x; Bsh[kv * 4 + 1][j] = v.y;
                Bsh[kv * 4 + 2][j] = v.z; Bsh[kv * 4 + 3][j] = v.w;
            }
            __syncthreads();
#pragma unroll
            for (int k = 0; k < FKC; ++k) {
                float4 av = *reinterpret_cast<const float4*>(&As[k][q0]);
                float4 bv = *reinterpret_cast<const float4*>(&Bsh[k][j0l]);
                float a[4] = {av.x, av.y, av.z, av.w};
                float bb[4] = {bv.x, bv.y, bv.z, bv.w};
#pragma unroll
                for (int qi = 0; qi < 4; ++qi)
#pragma unroll
                    for (int ji = 0; ji < 4; ++ji) acc[qi][ji] += a[qi] * bb[ji];
            }
        }
        bool full = (j0 + FJT <= N_BANK);
        if (full) {
            float4 inv = *reinterpret_cast<const float4*>(&inorm[j0 + j0l]);
            float iv[4] = {inv.x, inv.y, inv.z, inv.w};
#pragma unroll
            for (int qi = 0; qi < 4; ++qi) {
                int q = qbase + q0 + qi;
                float4 svv = *reinterpret_cast<const float4*>(
                    &svt[(size_t)q * N_BANK + j0 + j0l]);
                float s[4] = {svv.x, svv.y, svv.z, svv.w};
#pragma unroll
                for (int ji = 0; ji < 4; ++ji)
                    Ss[q0 + qi][j0l + ji] = 0.5f * (acc[qi][ji] * iv[ji]) + 0.5f * s[ji];
            }
        } else {
#pragma unroll
            for (int qi = 0; qi < 4; ++qi) {
                int q = qbase + q0 + qi;
#pragma unroll
                for (int ji = 0; ji < 4; ++ji) {
                    int jg = j0 + j0l + ji;
                    float s = -INFINITY;
                    if (jg < N_BANK)
                        s = 0.5f * (acc[qi][ji] * inorm[jg]) + 0.5f * svt[(size_t)q * N_BANK + jg];
                    Ss[q0 + qi][j0l + ji] = s;
                }
            }
        }
        __syncthreads();
        if (t < FBT) {
#pragma unroll 1
            for (int jj = 0; jj < FJT; ++jj) {
                int jg = j0 + jj;
                if (jg >= N_BANK) break;
                float s = Ss[t][jj];
                if (s > sc[K16 - 1] || (s == sc[K16 - 1] && jg < id[K16 - 1])) {
                    float cs = s; int ci = jg;
#pragma unroll
                    for (int i = 0; i < K16; ++i) {
                        bool bt2 = (cs > sc[i]) || (cs == sc[i] && ci < id[i]);
                        float ts = sc[i]; int ti = id[i];
                        if (bt2) { sc[i] = cs; id[i] = ci; cs = ts; ci = ti; }
                    }
                }
            }
        }
    }
    if (t < FBT) {
        int q = qbase + t;
        size_t base = ((size_t)q * FNS + slice) * K16;
#pragma unroll
        for (int i = 0; i < K16; ++i) { psc[base + i] = sc[i]; pid[base + i] = id[i]; }
    }
}

__global__ __launch_bounds__(256)
void fb_merge_kernel(const float* __restrict__ psc,
                     const int* __restrict__ pid,
                     const float* __restrict__ bank,
                     float* __restrict__ out) {
    __shared__ unsigned long long keys[FNS * K16];
    __shared__ unsigned long long wred[4];
    __shared__ int win[K16];
    int b = blockIdx.x, t = threadIdx.x;
    for (int i = t; i < FNS * K16; i += 256) {
        float s = psc[(size_t)b * FNS * K16 + i];
        unsigned int u = __float_as_uint(s);
        u ^= (u & 0x80000000u) ? 0xFFFFFFFFu : 0x80000000u;
        unsigned int iv = ~(unsigned int)pid[(size_t)b * FNS * K16 + i];
        keys[i] = ((unsigned long long)u << 32) | iv;
    }
    __syncthreads();
    for (int r = 0; r < K16; ++r) {
        unsigned long long best = 0ull;
        for (int i = t; i < FNS * K16; i += 256) best = umax64(best, keys[i]);
#pragma unroll
        for (int off = 32; off > 0; off >>= 1) best = umax64(best, shfl_down_u64(best, off));
        if ((t & 63) == 0) wred[t >> 6] = best;
        __syncthreads();
        unsigned long long w = umax64(umax64(wred[0], wred[1]), umax64(wred[2], wred[3]));
        if (t == 0) win[r] = (int)(~(unsigned int)w);
        for (int i = t; i < FNS * K16; i += 256)
            if (keys[i] == w) keys[i] = 0ull;
        __syncthreads();
    }
    if (t < K16)
        out[(size_t)B_Q * K16 * D_DIM + (size_t)b * K16 + t] = (float)win[t];
    const float4* bank4 = reinterpret_cast<const float4*>(bank);
    float4* out4 = reinterpret_cast<float4*>(out);
    for (int u = t; u < K16 * 64; u += 256) {
        int r = u >> 6, c = u & 63;
        out4[((size_t)b * K16 + r) * 64 + c] = bank4[(size_t)win[r] * 64 + c];
    }
}

// ---------------- launcher ----------------
extern "C" void kernel_launch(void* const* d_in, const int* in_sizes, int n_in,
                              void* d_out, int out_size, void* d_ws, size_t ws_size,
                              hipStream_t stream) {
    const float* z_ego = (const float*)d_in[0];
    const float* bank  = (const float*)d_in[1];
    const float* svt   = (const float*)d_in[2];
    const float* W     = (const float*)d_in[3];
    float* out = (float*)d_out;
    char* ws = (char*)d_ws;

    if (ws_size >= WS_NEED) {
        float* qn             = (float*)(ws + OFF_QN);
        unsigned short* qnt   = (unsigned short*)(ws + OFF_QNT);
        float* inorm          = (float*)(ws + OFF_INORM);
        float* th             = (float*)(ws + OFF_TH);
        float* gmax           = (float*)(ws + OFF_GMAX);
        unsigned short* bankt = (unsigned short*)(ws + OFF_BANKT);

        qn_prep_kernel<<<B_Q, 256, 0, stream>>>(z_ego, W, qn, qnt);
        prep_bank_kernel<<<NCHUNK, 256, 0, stream>>>(bank, inorm, bankt);
        screen2_kernel<<<NSL * 16, 256, 0, stream>>>(qnt, bankt, svt, gmax);
        gthresh_kernel<<<B_Q, 256, 0, stream>>>(gmax, th);
        grescore_kernel<<<B_Q, 256, 0, stream>>>(gmax, th, qn, inorm, bank, svt, out);
    } else {
        float* qn    = (float*)(ws + 0);
        float* inorm = (float*)(ws + FB_OFF_INORM);
        float* psc   = (float*)(ws + FB_OFF_PSC);
        int*   pid   = (int*)(ws + FB_OFF_PID);
        fb_qn_kernel<<<B_Q, 256, 0, stream>>>(z_ego, W, qn);
        inorm_kernel<<<(N_BANK + 3) / 4, 256, 0, stream>>>(bank, inorm);
        dim3 grid(FNS, B_Q / FBT);
        fb_score_topk_kernel<<<grid, 256, 0, stream>>>(qn, bank, svt, inorm, psc, pid);
        fb_merge_kernel<<<B_Q, 256, 0, stream>>>(psc, pid, bank, out);
    }
}